// Round 5
// baseline (3362.522 us; speedup 1.0000x reference)
//
#include <hip/hip_runtime.h>
#include <math.h>

// ---------------- problem constants ----------------
#define N_NODES 50000
#define N_EDGES 800000
#define NF 92           // node features
#define EF 41           // edge features
#define GF 180          // global attr
#define NHP 96          // padded bf16 node row

// node-GEMM: [50k,96] @ [96,384] (cols = Pf|Qf|Ps|Qs), KS_N=3, NT_N=24
#define WCN_ELEMS (3 * 24 * 64 * 8)   // 36864 per layer
// edge-GEMM: [800k,64] @ [64,192] (ea part only), KS_E=2, NT_E=12
#define WCE_ELEMS (2 * 12 * 64 * 8)   // 12288 per layer

typedef __attribute__((ext_vector_type(8))) short bf16x8;
typedef __attribute__((ext_vector_type(4))) float f32x4;

#define L2E 1.44269504f
#define LN2 0.69314718f

__device__ __forceinline__ float fast_sigmoid(float x) {
    return __builtin_amdgcn_rcpf(1.0f + __builtin_amdgcn_exp2f(-x * L2E));
}
__device__ __forceinline__ float fast_softplus(float x) {
    float t = __builtin_amdgcn_exp2f(-fabsf(x) * L2E);
    return fmaxf(x, 0.0f) + __builtin_amdgcn_logf(1.0f + t) * LN2;
}
__device__ __forceinline__ float fast_silu(float x) { return x * fast_sigmoid(x); }

__device__ __forceinline__ unsigned short f2bf(float x) {
    union { float f; unsigned u; } v; v.f = x;
    unsigned r = v.u + 0x7FFF + ((v.u >> 16) & 1);   // RNE
    return (unsigned short)(r >> 16);
}
__device__ __forceinline__ float bf2f(unsigned short h) {
    union { unsigned u; float f; } v; v.u = ((unsigned)h) << 16; return v.f;
}

// bijective XCD-aware block swizzle (m204 variant): blocks on the same XCD
// (bid%8) get a contiguous logical range.
__device__ __forceinline__ int xcd_swz(int bid, int nwg) {
    int q = nwg >> 3, r = nwg & 7;
    int xcd = bid & 7, idx = bid >> 3;
    return (xcd < r ? xcd * (q + 1) : r * (q + 1) + (xcd - r) * q) + idx;
}

// ---------------- sort infra: counting sort of edges by dst ----------------
__global__ __launch_bounds__(256) void hist_kernel(const int* __restrict__ ei,
                                                   int* __restrict__ bins)
{
    int e = blockIdx.x * 256 + threadIdx.x;
    if (e < N_EDGES) atomicAdd(&bins[ei[N_EDGES + e]], 1);
}

__global__ __launch_bounds__(1024) void scan_kernel(const int* __restrict__ bins,
                                                    int* __restrict__ cursor)
{
    __shared__ int tot[1024];
    const int t = threadIdx.x;
    const int C = (N_NODES + 1023) / 1024;
    const int i0 = t * C, i1 = min(i0 + C, N_NODES);
    int s = 0;
    for (int i = i0; i < i1; ++i) s += bins[i];
    tot[t] = s;
    __syncthreads();
    for (int off = 1; off < 1024; off <<= 1) {
        int v = (t >= off) ? tot[t - off] : 0;
        __syncthreads();
        tot[t] += v;
        __syncthreads();
    }
    int run = tot[t] - s;   // exclusive base
    for (int i = i0; i < i1; ++i) { cursor[i] = run; run += bins[i]; }
}

__global__ __launch_bounds__(256) void place_kernel(const int* __restrict__ ei,
                                                    int* __restrict__ cursor,
                                                    int* __restrict__ perm,
                                                    int* __restrict__ s_src,
                                                    int* __restrict__ s_dst)
{
    int e = blockIdx.x * 256 + threadIdx.x;
    if (e < N_EDGES) {
        int d = ei[N_EDGES + e];
        int pos = atomicAdd(&cursor[d], 1);
        perm[pos] = e;
        s_dst[pos] = d;
        s_src[pos] = ei[e];
    }
}

// ---------------- node-weight conversion: fragment-major hi/lo ----------------
__global__ __launch_bounds__(256) void convert_w_node(const float* __restrict__ Wf,
                                                      const float* __restrict__ Ws,
                                                      unsigned short* __restrict__ Wh,
                                                      unsigned short* __restrict__ Wl)
{
    int idx = blockIdx.x * 256 + threadIdx.x;
    if (idx >= WCN_ELEMS) return;
    int j    = idx & 7;
    int lane = (idx >> 3) & 63;
    int nt   = (idx >> 9) % 24;
    int ks   = idx / (24 * 512);
    int k = ks * 32 + ((lane >> 4) * 8) + j;
    int n = nt * 16 + (lane & 15);
    int t = n / 96, col = n % 96;
    float val = 0.f;
    if (k < 92 && col < 92) {
        const float* W = (t < 2) ? Wf : Ws;
        int rowoff = (t & 1) ? 92 : 0;
        val = W[(rowoff + k) * NF + col];
    }
    unsigned short hi = f2bf(val);
    Wh[idx] = hi;
    Wl[idx] = f2bf(val - bf2f(hi));
}

// ---------------- edge-weight conversion (W rows 184..224) ----------------
__global__ __launch_bounds__(256) void convert_w_edge(const float* __restrict__ Wf,
                                                      const float* __restrict__ Ws,
                                                      unsigned short* __restrict__ Wh,
                                                      unsigned short* __restrict__ Wl)
{
    int idx = blockIdx.x * 256 + threadIdx.x;
    if (idx >= WCE_ELEMS) return;
    int j    = idx & 7;
    int lane = (idx >> 3) & 63;
    int nt   = (idx >> 9) % 12;
    int ks   = idx / (12 * 512);
    int k = ks * 32 + ((lane >> 4) * 8) + j;
    int n = nt * 16 + (lane & 15);
    float val = 0.f;
    if (k < EF) {
        if (n < 92)                  val = Wf[(184 + k) * NF + n];
        else if (n >= 96 && n < 188) val = Ws[(184 + k) * NF + (n - 96)];
    }
    unsigned short hi = f2bf(val);
    Wh[idx] = hi;
    Wl[idx] = f2bf(val - bf2f(hi));
}

// ---------------- fp32 node features -> padded bf16 hi/lo rows ----------------
__global__ __launch_bounds__(256) void convert_x_k(const float* __restrict__ x,
                                                   unsigned short* __restrict__ hh,
                                                   unsigned short* __restrict__ hl)
{
    int i = blockIdx.x * 256 + threadIdx.x;
    if (i >= N_NODES * NHP) return;
    int n = i / NHP, c = i - n * NHP;
    float v = (c < NF) ? x[n * NF + c] : 0.0f;
    unsigned short hi = f2bf(v);
    hh[i] = hi;
    hl[i] = f2bf(v - bf2f(hi));
}

// ---------------- node GEMM -> interleaved tables ----------------
// D[node*96+col] = {Pf(dst,f)+bf, Ps(dst,s)+bs};  S[node*96+col] = {Qf(src,f), Qs(src,s)}
__global__ __launch_bounds__(384) void node_mfma(
    const unsigned short* __restrict__ hh, const unsigned short* __restrict__ hl,
    const unsigned short* __restrict__ Wh, const unsigned short* __restrict__ Wl,
    const float* __restrict__ bf, const float* __restrict__ bs,
    float* __restrict__ D, float* __restrict__ S)
{
    __shared__ char zz[2 * 64 * 256];     // hi | lo, 256B rows
    const int tid = threadIdx.x;
    const int n0 = blockIdx.x * 64;
    char* const zh = zz;
    char* const zl = zz + 64 * 256;

    for (int u = tid; u < 64 * 16; u += 384) {
        int e = u >> 4, c16 = u & 15;
        uint4 vh = make_uint4(0, 0, 0, 0), vl = vh;
        int node = n0 + e;
        if (c16 < 12 && node < N_NODES) {
            vh = *(const uint4*)(hh + (size_t)node * NHP + c16 * 8);
            vl = *(const uint4*)(hl + (size_t)node * NHP + c16 * 8);
        }
        int byte = (c16 * 16) ^ ((e & 7) << 4);
        *(uint4*)(zh + e * 256 + byte) = vh;
        *(uint4*)(zl + e * 256 + byte) = vl;
    }
    __syncthreads();

    const int w = tid >> 6, lane = tid & 63, lr = lane & 15, lg = lane >> 4;

    for (int ntx = 0; ntx < 4; ++ntx) {
        const int nt = w + 6 * ntx;
        f32x4 acc[4];
#pragma unroll
        for (int m = 0; m < 4; ++m) acc[m] = (f32x4){0.f, 0.f, 0.f, 0.f};

#pragma unroll
        for (int ks = 0; ks < 3; ++ks) {
            bf16x8 bh = *(const bf16x8*)(Wh + ((size_t)(ks * 24 + nt) * 64 + lane) * 8);
            bf16x8 bl = *(const bf16x8*)(Wl + ((size_t)(ks * 24 + nt) * 64 + lane) * 8);
#pragma unroll
            for (int m = 0; m < 4; ++m) {
                int row  = m * 16 + lr;
                int byte = (ks * 64 + lg * 16) ^ ((row & 7) << 4);
                bf16x8 ah = *(const bf16x8*)(zh + row * 256 + byte);
                bf16x8 al = *(const bf16x8*)(zl + row * 256 + byte);
                acc[m] = __builtin_amdgcn_mfma_f32_16x16x32_bf16(ah, bh, acc[m], 0, 0, 0);
                acc[m] = __builtin_amdgcn_mfma_f32_16x16x32_bf16(ah, bl, acc[m], 0, 0, 0);
                acc[m] = __builtin_amdgcn_mfma_f32_16x16x32_bf16(al, bh, acc[m], 0, 0, 0);
            }
        }

        // t: 0=Pf->D.x(+bf) 1=Qf->S.x 2=Ps->D.y(+bs) 3=Qs->S.y
        const int t = nt / 6, col = (nt % 6) * 16 + lr;
        if (col < NF) {
            float bias = (t == 0) ? bf[col] : ((t == 2) ? bs[col] : 0.f);
            float* base = (t & 1) ? S : D;
            int comp = t >> 1;
#pragma unroll
            for (int m = 0; m < 4; ++m)
#pragma unroll
                for (int r = 0; r < 4; ++r) {
                    int node = n0 + m * 16 + lg * 4 + r;
                    if (node < N_NODES)
                        base[((size_t)node * 96 + col) * 2 + comp] = acc[m][r] + bias;
                }
        }
    }
}

// ---------------- edge kernel: R = ea@We (MFMA) + D/S gather + act + atomic ----------------
// dst-sorted edges, XCD-swizzled blocks, native transcendentals.
__global__ __launch_bounds__(384) void edge_mfma3(
    const int* __restrict__ s_src, const int* __restrict__ s_dst,
    const int* __restrict__ perm, const float* __restrict__ ea,
    const unsigned short* __restrict__ Wh, const unsigned short* __restrict__ Wl,
    const float* __restrict__ D, const float* __restrict__ S,
    float* __restrict__ agg, int nblk)
{
    __shared__ char zz[2 * 64 * 128];     // ea hi | lo, 128B rows
    __shared__ int sdst[64], ssrc[64], sperm[64];

    const int tid = threadIdx.x;
    const int bid = xcd_swz(blockIdx.x, nblk);
    const long e0 = (long)bid * 64;
    char* const zh = zz;
    char* const zl = zz + 64 * 128;

    if (tid < 64) {
        sperm[tid] = perm[e0 + tid];
        ssrc[tid]  = s_src[e0 + tid];
        sdst[tid]  = s_dst[e0 + tid];
    }
    __syncthreads();

    // stage ea (gathered via perm; fp32 -> bf16 hi/lo), swizzled
    for (int u = tid; u < 64 * 8; u += 384) {
        int e = u >> 3, j = u & 7;
        const float* ear = ea + (size_t)sperm[e] * EF;
        unsigned short th[8], tl[8];
#pragma unroll
        for (int jj = 0; jj < 8; ++jj) {
            int cc = j * 8 + jj;
            float v = (cc < EF) ? ear[cc] : 0.0f;
            unsigned short hi = f2bf(v);
            th[jj] = hi;
            tl[jj] = f2bf(v - bf2f(hi));
        }
        int byte = (j * 16) ^ ((e & 7) << 4);
        *(uint4*)(zh + e * 128 + byte) = *(uint4*)th;
        *(uint4*)(zl + e * 128 + byte) = *(uint4*)tl;
    }
    __syncthreads();

    const int w = tid >> 6, lane = tid & 63, lr = lane & 15, lg = lane >> 4;

    f32x4 accF[4], accS[4];
#pragma unroll
    for (int m = 0; m < 4; ++m) {
        accF[m] = (f32x4){0.f, 0.f, 0.f, 0.f};
        accS[m] = (f32x4){0.f, 0.f, 0.f, 0.f};
    }

#pragma unroll
    for (int ks = 0; ks < 2; ++ks) {
        bf16x8 bFh = *(const bf16x8*)(Wh + ((size_t)(ks * 12 + w)     * 64 + lane) * 8);
        bf16x8 bFl = *(const bf16x8*)(Wl + ((size_t)(ks * 12 + w)     * 64 + lane) * 8);
        bf16x8 bSh = *(const bf16x8*)(Wh + ((size_t)(ks * 12 + w + 6) * 64 + lane) * 8);
        bf16x8 bSl = *(const bf16x8*)(Wl + ((size_t)(ks * 12 + w + 6) * 64 + lane) * 8);
#pragma unroll
        for (int m = 0; m < 4; ++m) {
            int row  = m * 16 + lr;
            int byte = (ks * 64 + lg * 16) ^ ((row & 7) << 4);
            bf16x8 ah = *(const bf16x8*)(zh + row * 128 + byte);
            bf16x8 al = *(const bf16x8*)(zl + row * 128 + byte);
            accF[m] = __builtin_amdgcn_mfma_f32_16x16x32_bf16(ah, bFh, accF[m], 0, 0, 0);
            accF[m] = __builtin_amdgcn_mfma_f32_16x16x32_bf16(ah, bFl, accF[m], 0, 0, 0);
            accF[m] = __builtin_amdgcn_mfma_f32_16x16x32_bf16(al, bFh, accF[m], 0, 0, 0);
            accS[m] = __builtin_amdgcn_mfma_f32_16x16x32_bf16(ah, bSh, accS[m], 0, 0, 0);
            accS[m] = __builtin_amdgcn_mfma_f32_16x16x32_bf16(ah, bSl, accS[m], 0, 0, 0);
            accS[m] = __builtin_amdgcn_mfma_f32_16x16x32_bf16(al, bSh, accS[m], 0, 0, 0);
        }
    }

    // epilogue: f/s = R + D[dst] + S[src] (biases folded into D); msg; atomic
    const int c = w * 16 + lr;
    if (c < NF) {
        const float2* D2 = (const float2*)D;
        const float2* S2 = (const float2*)S;
#pragma unroll
        for (int m = 0; m < 4; ++m) {
#pragma unroll
            for (int r = 0; r < 4; ++r) {
                int e = m * 16 + lg * 4 + r;
                int dst = sdst[e], src = ssrc[e];
                float2 dv = D2[(size_t)dst * 96 + c];
                float2 sv = S2[(size_t)src * 96 + c];
                float f = accF[m][r] + dv.x + sv.x;
                float s = accS[m][r] + dv.y + sv.y;
                float msg = fast_sigmoid(f) * fast_softplus(s);
                atomicAdd(&agg[(size_t)dst * NF + c], msg);
            }
        }
    }
}

// ---------------- residual + SiLU, fused bf16 hi/lo re-encode ----------------
__global__ __launch_bounds__(256) void node_update_fused(
    const float* __restrict__ xres, float* __restrict__ a,
    unsigned short* __restrict__ hh, unsigned short* __restrict__ hl)
{
    int i = blockIdx.x * 256 + threadIdx.x;
    int stride = gridDim.x * 256;
    for (; i < N_NODES * NF; i += stride) {
        int n = i / NF, cc = i - n * NF;
        float v = fast_silu(xres[i] + a[i]);
        a[i] = v;
        unsigned short hi = f2bf(v);
        hh[n * NHP + cc] = hi;
        hl[n * NHP + cc] = f2bf(v - bf2f(hi));
    }
}

// ---------------- fc1: hout = silu(hin @ W + b), [N,92]@[92,92] fp32 ----------------
__global__ __launch_bounds__(256) void fc_node_kernel(
    const float* __restrict__ hin, const float* __restrict__ W,
    const float* __restrict__ b, float* __restrict__ hout)
{
    __shared__ float xt[32][NF];
    __shared__ float wl[NF * NF];
    const int tid = threadIdx.x;
    const int nb = blockIdx.x * 32;

    for (int i = tid; i < NF * NF; i += 256) wl[i] = W[i];
    for (int i = tid; i < 32 * NF; i += 256) {
        int n = i / NF, k = i - n * NF;
        int node = nb + n;
        xt[n][k] = (node < N_NODES) ? hin[(long)node * NF + k] : 0.0f;
    }
    __syncthreads();

    for (int o = tid; o < 32 * NF; o += 256) {
        int n = o / NF, cc = o - n * NF;
        int node = nb + n;
        if (node < N_NODES) {
            float a = b[cc];
#pragma unroll 4
            for (int k = 0; k < NF; ++k) a = fmaf(xt[n][k], wl[k * NF + cc], a);
            hout[(long)node * NF + cc] = fast_silu(a);
        }
    }
}

// ---------------- mean pool ----------------
__global__ __launch_bounds__(256) void pool_kernel(const float* __restrict__ h,
                                                   float* __restrict__ pooled)
{
    const int c = blockIdx.x;
    float s = 0.0f;
    for (int n = threadIdx.x; n < N_NODES; n += 256) s += h[(long)n * NF + c];
    for (int off = 32; off; off >>= 1) s += __shfl_down(s, off);
    __shared__ float wsum[4];
    int wid = threadIdx.x >> 6;
    if ((threadIdx.x & 63) == 0) wsum[wid] = s;
    __syncthreads();
    if (threadIdx.x == 0)
        pooled[c] = (wsum[0] + wsum[1] + wsum[2] + wsum[3]) / (float)N_NODES;
}

// ---------------- final MLP head ----------------
__global__ __launch_bounds__(1024) void mlp_kernel(
    const float* __restrict__ pooled, const float* __restrict__ glob,
    const float* __restrict__ W2, const float* __restrict__ b2,
    const float* __restrict__ W3, const float* __restrict__ b3,
    const float* __restrict__ W4, const float* __restrict__ b4,
    const float* __restrict__ W5, const float* __restrict__ b5,
    const float* __restrict__ W6, const float* __restrict__ b6,
    const float* __restrict__ W7, const float* __restrict__ b7,
    float* __restrict__ out)
{
    __shared__ float vin[1024], vout[1024];
    const int t = threadIdx.x;

    if (t < NF) vin[t] = pooled[t];
    else if (t < NF + GF) vin[t] = glob[t - NF];
    __syncthreads();

    { // fc2: 272 -> 1024
        float a = b2[t];
        for (int k = 0; k < NF + GF; ++k) a = fmaf(vin[k], W2[k * 1024 + t], a);
        vout[t] = fast_silu(a);
    }
    __syncthreads();
    vin[t] = vout[t];
    __syncthreads();

    if (t < 512) { // fc3
        float a = b3[t];
        for (int k = 0; k < 1024; ++k) a = fmaf(vin[k], W3[k * 512 + t], a);
        vout[t] = fast_silu(a);
    }
    __syncthreads();
    if (t < 512) vin[t] = vout[t];
    __syncthreads();

    if (t < 256) { // fc4
        float a = b4[t];
        for (int k = 0; k < 512; ++k) a = fmaf(vin[k], W4[k * 256 + t], a);
        vout[t] = fast_silu(a);
    }
    __syncthreads();
    if (t < 256) vin[t] = vout[t];
    __syncthreads();

    if (t < 128) { // fc5
        float a = b5[t];
        for (int k = 0; k < 256; ++k) a = fmaf(vin[k], W5[k * 128 + t], a);
        vout[t] = fast_silu(a);
    }
    __syncthreads();
    if (t < 128) vin[t] = vout[t];
    __syncthreads();

    if (t < 64) { // fc6
        float a = b6[t];
        for (int k = 0; k < 128; ++k) a = fmaf(vin[k], W6[k * 64 + t], a);
        vout[t] = fast_silu(a);
    }
    __syncthreads();
    if (t < 64) vin[t] = vout[t];
    __syncthreads();

    if (t < 64) { // fc7: 64 -> 1
        float p = vin[t] * W7[t];
        for (int off = 32; off; off >>= 1) p += __shfl_down(p, off);
        if (t == 0) out[0] = p + b7[0];
    }
}

// ---------------- launch ----------------
extern "C" void kernel_launch(void* const* d_in, const int* in_sizes, int n_in,
                              void* d_out, int out_size, void* d_ws, size_t ws_size,
                              hipStream_t stream)
{
    (void)in_sizes; (void)n_in; (void)out_size; (void)ws_size;

    const float* x    = (const float*)d_in[0];
    const int*   ei   = (const int*)d_in[1];
    const float* ea   = (const float*)d_in[2];
    const float* glob = (const float*)d_in[3];
    const float* cWf[3] = {(const float*)d_in[5],  (const float*)d_in[9],  (const float*)d_in[13]};
    const float* cbf[3] = {(const float*)d_in[6],  (const float*)d_in[10], (const float*)d_in[14]};
    const float* cWs[3] = {(const float*)d_in[7],  (const float*)d_in[11], (const float*)d_in[15]};
    const float* cbs[3] = {(const float*)d_in[8],  (const float*)d_in[12], (const float*)d_in[16]};
    const float* fc1W = (const float*)d_in[17]; const float* fc1b = (const float*)d_in[18];
    const float* W2 = (const float*)d_in[19];   const float* b2 = (const float*)d_in[20];
    const float* W3 = (const float*)d_in[21];   const float* b3 = (const float*)d_in[22];
    const float* W4 = (const float*)d_in[23];   const float* b4 = (const float*)d_in[24];
    const float* W5 = (const float*)d_in[25];   const float* b5 = (const float*)d_in[26];
    const float* W6 = (const float*)d_in[27];   const float* b6 = (const float*)d_in[28];
    const float* W7 = (const float*)d_in[29];   const float* b7 = (const float*)d_in[30];
    float* out = (float*)d_out;

    const size_t H = (size_t)N_NODES * NF;
    float* b0 = (float*)d_ws;                                // [N,92] fp32
    float* b1 = b0 + H;
    float* pooled = b1 + H;                                  // 128 floats
    unsigned short* hh   = (unsigned short*)(pooled + 128);  // N*96 bf16 hi
    unsigned short* hl   = hh + (size_t)N_NODES * NHP;       // N*96 bf16 lo
    unsigned short* WcNh = hl + (size_t)N_NODES * NHP;       // 3*36864
    unsigned short* WcNl = WcNh + 3 * (size_t)WCN_ELEMS;
    unsigned short* WcEh = WcNl + 3 * (size_t)WCN_ELEMS;     // 3*12288
    unsigned short* WcEl = WcEh + 3 * (size_t)WCE_ELEMS;
    float* D = (float*)(WcEl + 3 * (size_t)WCE_ELEMS);       // N*96 float2
    float* S = D + (size_t)2 * N_NODES * 96;                 // N*96 float2
    int* bins   = (int*)(S + (size_t)2 * N_NODES * 96);
    int* cursor = bins + N_NODES;
    int* perm   = cursor + N_NODES;
    int* s_src  = perm + N_EDGES;
    int* s_dst  = s_src + N_EDGES;

    const size_t HB = H * sizeof(float);
    const int nEdgeBlocks = N_EDGES / 64;                    // 12500
    const int nNodeBlocks = (N_NODES + 63) / 64;             // 782
    const int fcBlocks = (N_NODES + 31) / 32;

    // one-time: sort edges by dst (hist -> scan -> place)
    hipMemsetAsync(bins, 0, N_NODES * sizeof(int), stream);
    hist_kernel<<<(N_EDGES + 255) / 256, 256, 0, stream>>>(ei, bins);
    scan_kernel<<<1, 1024, 0, stream>>>(bins, cursor);
    place_kernel<<<(N_EDGES + 255) / 256, 256, 0, stream>>>(ei, cursor, perm, s_src, s_dst);

    // one-time conversions
    for (int l = 0; l < 3; ++l) {
        convert_w_node<<<(WCN_ELEMS + 255) / 256, 256, 0, stream>>>(
            cWf[l], cWs[l], WcNh + (size_t)l * WCN_ELEMS, WcNl + (size_t)l * WCN_ELEMS);
        convert_w_edge<<<(WCE_ELEMS + 255) / 256, 256, 0, stream>>>(
            cWf[l], cWs[l], WcEh + (size_t)l * WCE_ELEMS, WcEl + (size_t)l * WCE_ELEMS);
    }
    convert_x_k<<<(N_NODES * NHP + 255) / 256, 256, 0, stream>>>(x, hh, hl);

    for (int l = 0; l < 3; ++l) {
        const float* xres = (l == 0) ? x : ((l == 1) ? b0 : b1);
        float* aggb = (l == 1) ? b1 : b0;    // l0->b0, l1->b1, l2->b0
        node_mfma<<<nNodeBlocks, 384, 0, stream>>>(hh, hl,
            WcNh + (size_t)l * WCN_ELEMS, WcNl + (size_t)l * WCN_ELEMS,
            cbf[l], cbs[l], D, S);
        hipMemsetAsync(aggb, 0, HB, stream);
        edge_mfma3<<<nEdgeBlocks, 384, 0, stream>>>(s_src, s_dst, perm, ea,
            WcEh + (size_t)l * WCE_ELEMS, WcEl + (size_t)l * WCE_ELEMS,
            D, S, aggb, nEdgeBlocks);
        node_update_fused<<<2048, 256, 0, stream>>>(xres, aggb, hh, hl);
    }

    // fc1 twice: b0 -> b1 -> b0
    fc_node_kernel<<<fcBlocks, 256, 0, stream>>>(b0, fc1W, fc1b, b1);
    fc_node_kernel<<<fcBlocks, 256, 0, stream>>>(b1, fc1W, fc1b, b0);

    pool_kernel<<<NF, 256, 0, stream>>>(b0, pooled);
    mlp_kernel<<<1, 1024, 0, stream>>>(pooled, glob, W2, b2, W3, b3, W4, b4,
                                       W5, b5, W6, b6, W7, b7, out);
}

// Round 6
// 1788.055 us; speedup vs baseline: 1.8805x; 1.8805x over previous
//
#include <hip/hip_runtime.h>
#include <math.h>

// ---------------- problem constants ----------------
#define N_NODES 50000
#define N_EDGES 800000
#define NF 92           // node features
#define EF 41           // edge features
#define GF 180          // global attr
#define NHP 96          // padded bf16 node row
#define NEP 48          // padded bf16 edge_attr row (dst-sorted eb)

// node-GEMM: [50k,96] @ [96,384] (cols = Pf|Qf|Ps|Qs), KS_N=3, NT_N=24
#define WCN_ELEMS (3 * 24 * 64 * 8)   // 36864 per layer
// edge-GEMM: [800k,64] @ [64,192] (ea part only), KS_E=2, NT_E=12
#define WCE_ELEMS (2 * 12 * 64 * 8)   // 12288 per layer

typedef __attribute__((ext_vector_type(8))) short bf16x8;
typedef __attribute__((ext_vector_type(4))) float f32x4;

#define L2E 1.44269504f
#define LN2 0.69314718f

__device__ __forceinline__ float fast_sigmoid(float x) {
    return __builtin_amdgcn_rcpf(1.0f + __builtin_amdgcn_exp2f(-x * L2E));
}
__device__ __forceinline__ float fast_softplus(float x) {
    float t = __builtin_amdgcn_exp2f(-fabsf(x) * L2E);
    return fmaxf(x, 0.0f) + __builtin_amdgcn_logf(1.0f + t) * LN2;
}
__device__ __forceinline__ float fast_silu(float x) { return x * fast_sigmoid(x); }

__device__ __forceinline__ unsigned short f2bf(float x) {
    union { float f; unsigned u; } v; v.f = x;
    unsigned r = v.u + 0x7FFF + ((v.u >> 16) & 1);   // RNE
    return (unsigned short)(r >> 16);
}
__device__ __forceinline__ float bf2f(unsigned short h) {
    union { unsigned u; float f; } v; v.u = ((unsigned)h) << 16; return v.f;
}

// bijective XCD-aware block swizzle (m204 variant)
__device__ __forceinline__ int xcd_swz(int bid, int nwg) {
    int q = nwg >> 3, r = nwg & 7;
    int xcd = bid & 7, idx = bid >> 3;
    return (xcd < r ? xcd * (q + 1) : r * (q + 1) + (xcd - r) * q) + idx;
}

// ---------------- sort infra: counting sort of edges by dst ----------------
__global__ __launch_bounds__(256) void hist_kernel(const int* __restrict__ ei,
                                                   int* __restrict__ bins)
{
    int e = blockIdx.x * 256 + threadIdx.x;
    if (e < N_EDGES) atomicAdd(&bins[ei[N_EDGES + e]], 1);
}

__global__ __launch_bounds__(1024) void scan_kernel(const int* __restrict__ bins,
                                                    int* __restrict__ cursor)
{
    __shared__ int tot[1024];
    const int t = threadIdx.x;
    const int C = (N_NODES + 1023) / 1024;
    const int i0 = t * C, i1 = min(i0 + C, N_NODES);
    int s = 0;
    for (int i = i0; i < i1; ++i) s += bins[i];
    tot[t] = s;
    __syncthreads();
    for (int off = 1; off < 1024; off <<= 1) {
        int v = (t >= off) ? tot[t - off] : 0;
        __syncthreads();
        tot[t] += v;
        __syncthreads();
    }
    int run = tot[t] - s;   // exclusive base
    for (int i = i0; i < i1; ++i) { cursor[i] = run; run += bins[i]; }
}

__global__ __launch_bounds__(256) void place_kernel(const int* __restrict__ ei,
                                                    int* __restrict__ cursor,
                                                    int* __restrict__ perm,
                                                    int* __restrict__ s_src,
                                                    int* __restrict__ s_dst)
{
    int e = blockIdx.x * 256 + threadIdx.x;
    if (e < N_EDGES) {
        int d = ei[N_EDGES + e];
        int pos = atomicAdd(&cursor[d], 1);
        perm[pos] = e;
        s_dst[pos] = d;
        s_src[pos] = ei[e];
    }
}

// ---------------- one-time: permute ea into dst-sorted bf16 hi/lo rows ----------------
__global__ __launch_bounds__(256) void permute_ea(const float* __restrict__ ea,
                                                  const int* __restrict__ perm,
                                                  unsigned short* __restrict__ ebh,
                                                  unsigned short* __restrict__ ebl)
{
    long i = (long)blockIdx.x * 256 + threadIdx.x;
    if (i >= (long)N_EDGES * NEP) return;
    long e = i / NEP; int c = (int)(i - e * NEP);
    float v = (c < EF) ? ea[(size_t)perm[e] * EF + c] : 0.0f;
    unsigned short hi = f2bf(v);
    ebh[i] = hi;
    ebl[i] = f2bf(v - bf2f(hi));
}

// ---------------- node-weight conversion: fragment-major hi/lo ----------------
__global__ __launch_bounds__(256) void convert_w_node(const float* __restrict__ Wf,
                                                      const float* __restrict__ Ws,
                                                      unsigned short* __restrict__ Wh,
                                                      unsigned short* __restrict__ Wl)
{
    int idx = blockIdx.x * 256 + threadIdx.x;
    if (idx >= WCN_ELEMS) return;
    int j    = idx & 7;
    int lane = (idx >> 3) & 63;
    int nt   = (idx >> 9) % 24;
    int ks   = idx / (24 * 512);
    int k = ks * 32 + ((lane >> 4) * 8) + j;
    int n = nt * 16 + (lane & 15);
    int t = n / 96, col = n % 96;
    float val = 0.f;
    if (k < 92 && col < 92) {
        const float* W = (t < 2) ? Wf : Ws;
        int rowoff = (t & 1) ? 92 : 0;
        val = W[(rowoff + k) * NF + col];
    }
    unsigned short hi = f2bf(val);
    Wh[idx] = hi;
    Wl[idx] = f2bf(val - bf2f(hi));
}

// ---------------- edge-weight conversion (W rows 184..224) ----------------
__global__ __launch_bounds__(256) void convert_w_edge(const float* __restrict__ Wf,
                                                      const float* __restrict__ Ws,
                                                      unsigned short* __restrict__ Wh,
                                                      unsigned short* __restrict__ Wl)
{
    int idx = blockIdx.x * 256 + threadIdx.x;
    if (idx >= WCE_ELEMS) return;
    int j    = idx & 7;
    int lane = (idx >> 3) & 63;
    int nt   = (idx >> 9) % 12;
    int ks   = idx / (12 * 512);
    int k = ks * 32 + ((lane >> 4) * 8) + j;
    int n = nt * 16 + (lane & 15);
    float val = 0.f;
    if (k < EF) {
        if (n < 92)                  val = Wf[(184 + k) * NF + n];
        else if (n >= 96 && n < 188) val = Ws[(184 + k) * NF + (n - 96)];
    }
    unsigned short hi = f2bf(val);
    Wh[idx] = hi;
    Wl[idx] = f2bf(val - bf2f(hi));
}

// ---------------- fp32 node features -> padded bf16 hi/lo rows ----------------
__global__ __launch_bounds__(256) void convert_x_k(const float* __restrict__ x,
                                                   unsigned short* __restrict__ hh,
                                                   unsigned short* __restrict__ hl)
{
    int i = blockIdx.x * 256 + threadIdx.x;
    if (i >= N_NODES * NHP) return;
    int n = i / NHP, c = i - n * NHP;
    float v = (c < NF) ? x[n * NF + c] : 0.0f;
    unsigned short hi = f2bf(v);
    hh[i] = hi;
    hl[i] = f2bf(v - bf2f(hi));
}

// ---------------- node GEMM -> interleaved tables ----------------
// D[node*96+col] = {Pf+bf, Ps+bs} (dst side);  S[node*96+col] = {Qf, Qs} (src side)
__global__ __launch_bounds__(384) void node_mfma(
    const unsigned short* __restrict__ hh, const unsigned short* __restrict__ hl,
    const unsigned short* __restrict__ Wh, const unsigned short* __restrict__ Wl,
    const float* __restrict__ bf, const float* __restrict__ bs,
    float* __restrict__ D, float* __restrict__ S)
{
    __shared__ char zz[2 * 64 * 256];     // hi | lo, 256B rows
    const int tid = threadIdx.x;
    const int n0 = blockIdx.x * 64;
    char* const zh = zz;
    char* const zl = zz + 64 * 256;

    for (int u = tid; u < 64 * 16; u += 384) {
        int e = u >> 4, c16 = u & 15;
        uint4 vh = make_uint4(0, 0, 0, 0), vl = vh;
        int node = n0 + e;
        if (c16 < 12 && node < N_NODES) {
            vh = *(const uint4*)(hh + (size_t)node * NHP + c16 * 8);
            vl = *(const uint4*)(hl + (size_t)node * NHP + c16 * 8);
        }
        int byte = (c16 * 16) ^ ((e & 7) << 4);
        *(uint4*)(zh + e * 256 + byte) = vh;
        *(uint4*)(zl + e * 256 + byte) = vl;
    }
    __syncthreads();

    const int w = tid >> 6, lane = tid & 63, lr = lane & 15, lg = lane >> 4;

    for (int ntx = 0; ntx < 4; ++ntx) {
        const int nt = w + 6 * ntx;
        f32x4 acc[4];
#pragma unroll
        for (int m = 0; m < 4; ++m) acc[m] = (f32x4){0.f, 0.f, 0.f, 0.f};

#pragma unroll
        for (int ks = 0; ks < 3; ++ks) {
            bf16x8 bh = *(const bf16x8*)(Wh + ((size_t)(ks * 24 + nt) * 64 + lane) * 8);
            bf16x8 bl = *(const bf16x8*)(Wl + ((size_t)(ks * 24 + nt) * 64 + lane) * 8);
#pragma unroll
            for (int m = 0; m < 4; ++m) {
                int row  = m * 16 + lr;
                int byte = (ks * 64 + lg * 16) ^ ((row & 7) << 4);
                bf16x8 ah = *(const bf16x8*)(zh + row * 256 + byte);
                bf16x8 al = *(const bf16x8*)(zl + row * 256 + byte);
                acc[m] = __builtin_amdgcn_mfma_f32_16x16x32_bf16(ah, bh, acc[m], 0, 0, 0);
                acc[m] = __builtin_amdgcn_mfma_f32_16x16x32_bf16(ah, bl, acc[m], 0, 0, 0);
                acc[m] = __builtin_amdgcn_mfma_f32_16x16x32_bf16(al, bh, acc[m], 0, 0, 0);
            }
        }

        // t: 0=Pf->D.x(+bf) 1=Qf->S.x 2=Ps->D.y(+bs) 3=Qs->S.y
        const int t = nt / 6, col = (nt % 6) * 16 + lr;
        if (col < NF) {
            float bias = (t == 0) ? bf[col] : ((t == 2) ? bs[col] : 0.f);
            float* base = (t & 1) ? S : D;
            int comp = t >> 1;
#pragma unroll
            for (int m = 0; m < 4; ++m)
#pragma unroll
                for (int r = 0; r < 4; ++r) {
                    int node = n0 + m * 16 + lg * 4 + r;
                    if (node < N_NODES)
                        base[((size_t)node * 96 + col) * 2 + comp] = acc[m][r] + bias;
                }
        }
    }
}

// ---------------- edge kernel ----------------
// dst-sorted edges. EB=true: stream pre-permuted bf16 eb rows (fast path).
// EB=false: gather ea rows via perm (fallback). Atomics merged over equal-dst runs.
template <bool EB>
__global__ __launch_bounds__(384) void edge_mfma4(
    const int* __restrict__ s_src, const int* __restrict__ s_dst,
    const int* __restrict__ perm, const float* __restrict__ ea,
    const unsigned short* __restrict__ ebh, const unsigned short* __restrict__ ebl,
    const unsigned short* __restrict__ Wh, const unsigned short* __restrict__ Wl,
    const float* __restrict__ D, const float* __restrict__ S,
    float* __restrict__ agg, int nblk)
{
    __shared__ char zz[2 * 64 * 128];     // ea hi | lo, 128B rows
    __shared__ int sdst[64], ssrc[64], sperm[64];

    const int tid = threadIdx.x;
    const int bid = xcd_swz(blockIdx.x, nblk);
    const size_t e0 = (size_t)bid * 64;
    char* const zh = zz;
    char* const zl = zz + 64 * 128;

    if (tid < 64) {
        ssrc[tid] = s_src[e0 + tid];
        sdst[tid] = s_dst[e0 + tid];
        if (!EB) sperm[tid] = perm[e0 + tid];
    }
    __syncthreads();

    if (EB) {
        // streaming copy of pre-converted bf16 rows (sequential in memory)
        for (int u = tid; u < 64 * 8; u += 384) {
            int e = u >> 3, j = u & 7;
            uint4 vh = make_uint4(0, 0, 0, 0), vl = vh;
            if (j < 6) {
                vh = *(const uint4*)(ebh + (e0 + e) * NEP + j * 8);
                vl = *(const uint4*)(ebl + (e0 + e) * NEP + j * 8);
            }
            int byte = (j * 16) ^ ((e & 7) << 4);
            *(uint4*)(zh + e * 128 + byte) = vh;
            *(uint4*)(zl + e * 128 + byte) = vl;
        }
    } else {
        for (int u = tid; u < 64 * 8; u += 384) {
            int e = u >> 3, j = u & 7;
            const float* ear = ea + (size_t)sperm[e] * EF;
            unsigned short th[8], tl[8];
#pragma unroll
            for (int jj = 0; jj < 8; ++jj) {
                int cc = j * 8 + jj;
                float v = (cc < EF) ? ear[cc] : 0.0f;
                unsigned short hi = f2bf(v);
                th[jj] = hi;
                tl[jj] = f2bf(v - bf2f(hi));
            }
            int byte = (j * 16) ^ ((e & 7) << 4);
            *(uint4*)(zh + e * 128 + byte) = *(uint4*)th;
            *(uint4*)(zl + e * 128 + byte) = *(uint4*)tl;
        }
    }
    __syncthreads();

    const int w = tid >> 6, lane = tid & 63, lr = lane & 15, lg = lane >> 4;

    f32x4 accF[4], accS[4];
#pragma unroll
    for (int m = 0; m < 4; ++m) {
        accF[m] = (f32x4){0.f, 0.f, 0.f, 0.f};
        accS[m] = (f32x4){0.f, 0.f, 0.f, 0.f};
    }

#pragma unroll
    for (int ks = 0; ks < 2; ++ks) {
        bf16x8 bFh = *(const bf16x8*)(Wh + ((size_t)(ks * 12 + w)     * 64 + lane) * 8);
        bf16x8 bFl = *(const bf16x8*)(Wl + ((size_t)(ks * 12 + w)     * 64 + lane) * 8);
        bf16x8 bSh = *(const bf16x8*)(Wh + ((size_t)(ks * 12 + w + 6) * 64 + lane) * 8);
        bf16x8 bSl = *(const bf16x8*)(Wl + ((size_t)(ks * 12 + w + 6) * 64 + lane) * 8);
#pragma unroll
        for (int m = 0; m < 4; ++m) {
            int row  = m * 16 + lr;
            int byte = (ks * 64 + lg * 16) ^ ((row & 7) << 4);
            bf16x8 ah = *(const bf16x8*)(zh + row * 128 + byte);
            bf16x8 al = *(const bf16x8*)(zl + row * 128 + byte);
            accF[m] = __builtin_amdgcn_mfma_f32_16x16x32_bf16(ah, bFh, accF[m], 0, 0, 0);
            accF[m] = __builtin_amdgcn_mfma_f32_16x16x32_bf16(ah, bFl, accF[m], 0, 0, 0);
            accF[m] = __builtin_amdgcn_mfma_f32_16x16x32_bf16(al, bFh, accF[m], 0, 0, 0);
            accS[m] = __builtin_amdgcn_mfma_f32_16x16x32_bf16(ah, bSh, accS[m], 0, 0, 0);
            accS[m] = __builtin_amdgcn_mfma_f32_16x16x32_bf16(ah, bSl, accS[m], 0, 0, 0);
            accS[m] = __builtin_amdgcn_mfma_f32_16x16x32_bf16(al, bSh, accS[m], 0, 0, 0);
        }
    }

    // epilogue: f/s = R + D[dst] + S[src]; merge atomics over equal-dst runs
    const int c = w * 16 + lr;
    if (c < NF) {
        const float2* D2 = (const float2*)D;
        const float2* S2 = (const float2*)S;
#pragma unroll
        for (int m = 0; m < 4; ++m) {
            const int eb0 = m * 16 + lg * 4;
            int prev = sdst[eb0];
            float2 dv = D2[(size_t)prev * 96 + c];
            float accum = 0.f;
#pragma unroll
            for (int r = 0; r < 4; ++r) {
                int e = eb0 + r;
                int dst = sdst[e];
                if (dst != prev) {
                    atomicAdd(&agg[(size_t)prev * NF + c], accum);
                    accum = 0.f;
                    prev = dst;
                    dv = D2[(size_t)dst * 96 + c];
                }
                float2 sv = S2[(size_t)ssrc[e] * 96 + c];
                float f = accF[m][r] + dv.x + sv.x;
                float s = accS[m][r] + dv.y + sv.y;
                accum += fast_sigmoid(f) * fast_softplus(s);
            }
            atomicAdd(&agg[(size_t)prev * NF + c], accum);
        }
    }
}

// ---------------- residual + SiLU, fused bf16 hi/lo re-encode ----------------
__global__ __launch_bounds__(256) void node_update_fused(
    const float* __restrict__ xres, float* __restrict__ a,
    unsigned short* __restrict__ hh, unsigned short* __restrict__ hl)
{
    int i = blockIdx.x * 256 + threadIdx.x;
    int stride = gridDim.x * 256;
    for (; i < N_NODES * NF; i += stride) {
        int n = i / NF, cc = i - n * NF;
        float v = fast_silu(xres[i] + a[i]);
        a[i] = v;
        unsigned short hi = f2bf(v);
        hh[n * NHP + cc] = hi;
        hl[n * NHP + cc] = f2bf(v - bf2f(hi));
    }
}

// ---------------- fc1: hout = silu(hin @ W + b), [N,92]@[92,92] fp32 ----------------
__global__ __launch_bounds__(256) void fc_node_kernel(
    const float* __restrict__ hin, const float* __restrict__ W,
    const float* __restrict__ b, float* __restrict__ hout)
{
    __shared__ float xt[32][NF];
    __shared__ float wl[NF * NF];
    const int tid = threadIdx.x;
    const int nb = blockIdx.x * 32;

    for (int i = tid; i < NF * NF; i += 256) wl[i] = W[i];
    for (int i = tid; i < 32 * NF; i += 256) {
        int n = i / NF, k = i - n * NF;
        int node = nb + n;
        xt[n][k] = (node < N_NODES) ? hin[(long)node * NF + k] : 0.0f;
    }
    __syncthreads();

    for (int o = tid; o < 32 * NF; o += 256) {
        int n = o / NF, cc = o - n * NF;
        int node = nb + n;
        if (node < N_NODES) {
            float a = b[cc];
#pragma unroll 4
            for (int k = 0; k < NF; ++k) a = fmaf(xt[n][k], wl[k * NF + cc], a);
            hout[(long)node * NF + cc] = fast_silu(a);
        }
    }
}

// ---------------- mean pool ----------------
__global__ __launch_bounds__(256) void pool_kernel(const float* __restrict__ h,
                                                   float* __restrict__ pooled)
{
    const int c = blockIdx.x;
    float s = 0.0f;
    for (int n = threadIdx.x; n < N_NODES; n += 256) s += h[(long)n * NF + c];
    for (int off = 32; off; off >>= 1) s += __shfl_down(s, off);
    __shared__ float wsum[4];
    int wid = threadIdx.x >> 6;
    if ((threadIdx.x & 63) == 0) wsum[wid] = s;
    __syncthreads();
    if (threadIdx.x == 0)
        pooled[c] = (wsum[0] + wsum[1] + wsum[2] + wsum[3]) / (float)N_NODES;
}

// ---------------- final MLP head ----------------
__global__ __launch_bounds__(1024) void mlp_kernel(
    const float* __restrict__ pooled, const float* __restrict__ glob,
    const float* __restrict__ W2, const float* __restrict__ b2,
    const float* __restrict__ W3, const float* __restrict__ b3,
    const float* __restrict__ W4, const float* __restrict__ b4,
    const float* __restrict__ W5, const float* __restrict__ b5,
    const float* __restrict__ W6, const float* __restrict__ b6,
    const float* __restrict__ W7, const float* __restrict__ b7,
    float* __restrict__ out)
{
    __shared__ float vin[1024], vout[1024];
    const int t = threadIdx.x;

    if (t < NF) vin[t] = pooled[t];
    else if (t < NF + GF) vin[t] = glob[t - NF];
    __syncthreads();

    { // fc2: 272 -> 1024
        float a = b2[t];
        for (int k = 0; k < NF + GF; ++k) a = fmaf(vin[k], W2[k * 1024 + t], a);
        vout[t] = fast_silu(a);
    }
    __syncthreads();
    vin[t] = vout[t];
    __syncthreads();

    if (t < 512) { // fc3
        float a = b3[t];
        for (int k = 0; k < 1024; ++k) a = fmaf(vin[k], W3[k * 512 + t], a);
        vout[t] = fast_silu(a);
    }
    __syncthreads();
    if (t < 512) vin[t] = vout[t];
    __syncthreads();

    if (t < 256) { // fc4
        float a = b4[t];
        for (int k = 0; k < 512; ++k) a = fmaf(vin[k], W4[k * 256 + t], a);
        vout[t] = fast_silu(a);
    }
    __syncthreads();
    if (t < 256) vin[t] = vout[t];
    __syncthreads();

    if (t < 128) { // fc5
        float a = b5[t];
        for (int k = 0; k < 256; ++k) a = fmaf(vin[k], W5[k * 128 + t], a);
        vout[t] = fast_silu(a);
    }
    __syncthreads();
    if (t < 128) vin[t] = vout[t];
    __syncthreads();

    if (t < 64) { // fc6
        float a = b6[t];
        for (int k = 0; k < 128; ++k) a = fmaf(vin[k], W6[k * 64 + t], a);
        vout[t] = fast_silu(a);
    }
    __syncthreads();
    if (t < 64) vin[t] = vout[t];
    __syncthreads();

    if (t < 64) { // fc7: 64 -> 1
        float p = vin[t] * W7[t];
        for (int off = 32; off; off >>= 1) p += __shfl_down(p, off);
        if (t == 0) out[0] = p + b7[0];
    }
}

// ---------------- launch ----------------
extern "C" void kernel_launch(void* const* d_in, const int* in_sizes, int n_in,
                              void* d_out, int out_size, void* d_ws, size_t ws_size,
                              hipStream_t stream)
{
    (void)in_sizes; (void)n_in; (void)out_size;

    const float* x    = (const float*)d_in[0];
    const int*   ei   = (const int*)d_in[1];
    const float* ea   = (const float*)d_in[2];
    const float* glob = (const float*)d_in[3];
    const float* cWf[3] = {(const float*)d_in[5],  (const float*)d_in[9],  (const float*)d_in[13]};
    const float* cbf[3] = {(const float*)d_in[6],  (const float*)d_in[10], (const float*)d_in[14]};
    const float* cWs[3] = {(const float*)d_in[7],  (const float*)d_in[11], (const float*)d_in[15]};
    const float* cbs[3] = {(const float*)d_in[8],  (const float*)d_in[12], (const float*)d_in[16]};
    const float* fc1W = (const float*)d_in[17]; const float* fc1b = (const float*)d_in[18];
    const float* W2 = (const float*)d_in[19];   const float* b2 = (const float*)d_in[20];
    const float* W3 = (const float*)d_in[21];   const float* b3 = (const float*)d_in[22];
    const float* W4 = (const float*)d_in[23];   const float* b4 = (const float*)d_in[24];
    const float* W5 = (const float*)d_in[25];   const float* b5 = (const float*)d_in[26];
    const float* W6 = (const float*)d_in[27];   const float* b6 = (const float*)d_in[28];
    const float* W7 = (const float*)d_in[29];   const float* b7 = (const float*)d_in[30];
    float* out = (float*)d_out;

    const size_t H = (size_t)N_NODES * NF;
    float* b0 = (float*)d_ws;                                // [N,92] fp32
    float* b1 = b0 + H;
    float* pooled = b1 + H;                                  // 128 floats
    unsigned short* hh   = (unsigned short*)(pooled + 128);  // N*96 bf16 hi
    unsigned short* hl   = hh + (size_t)N_NODES * NHP;       // N*96 bf16 lo
    unsigned short* WcNh = hl + (size_t)N_NODES * NHP;       // 3*36864
    unsigned short* WcNl = WcNh + 3 * (size_t)WCN_ELEMS;
    unsigned short* WcEh = WcNl + 3 * (size_t)WCN_ELEMS;     // 3*12288
    unsigned short* WcEl = WcEh + 3 * (size_t)WCE_ELEMS;
    float* D = (float*)(WcEl + 3 * (size_t)WCE_ELEMS);       // N*96 float2
    float* S = D + (size_t)2 * N_NODES * 96;                 // N*96 float2
    int* bins   = (int*)(S + (size_t)2 * N_NODES * 96);
    int* cursor = bins + N_NODES;
    int* perm   = cursor + N_NODES;
    int* s_src  = perm + N_EDGES;
    int* s_dst  = s_src + N_EDGES;
    unsigned short* ebh = (unsigned short*)(s_dst + N_EDGES);  // E*48 bf16 hi (sorted)
    unsigned short* ebl = ebh + (size_t)N_EDGES * NEP;
    const size_t need_full = (size_t)((char*)(ebl + (size_t)N_EDGES * NEP) - (char*)d_ws);
    const bool use_eb = ws_size >= need_full;

    const size_t HB = H * sizeof(float);
    const int nEdgeBlocks = N_EDGES / 64;                    // 12500
    const int nNodeBlocks = (N_NODES + 63) / 64;             // 782
    const int fcBlocks = (N_NODES + 31) / 32;

    // one-time: sort edges by dst (hist -> scan -> place), then permute ea
    hipMemsetAsync(bins, 0, N_NODES * sizeof(int), stream);
    hist_kernel<<<(N_EDGES + 255) / 256, 256, 0, stream>>>(ei, bins);
    scan_kernel<<<1, 1024, 0, stream>>>(bins, cursor);
    place_kernel<<<(N_EDGES + 255) / 256, 256, 0, stream>>>(ei, cursor, perm, s_src, s_dst);
    if (use_eb)
        permute_ea<<<(int)(((long)N_EDGES * NEP + 255) / 256), 256, 0, stream>>>(ea, perm, ebh, ebl);

    // one-time conversions
    for (int l = 0; l < 3; ++l) {
        convert_w_node<<<(WCN_ELEMS + 255) / 256, 256, 0, stream>>>(
            cWf[l], cWs[l], WcNh + (size_t)l * WCN_ELEMS, WcNl + (size_t)l * WCN_ELEMS);
        convert_w_edge<<<(WCE_ELEMS + 255) / 256, 256, 0, stream>>>(
            cWf[l], cWs[l], WcEh + (size_t)l * WCE_ELEMS, WcEl + (size_t)l * WCE_ELEMS);
    }
    convert_x_k<<<(N_NODES * NHP + 255) / 256, 256, 0, stream>>>(x, hh, hl);

    for (int l = 0; l < 3; ++l) {
        const float* xres = (l == 0) ? x : ((l == 1) ? b0 : b1);
        float* aggb = (l == 1) ? b1 : b0;    // l0->b0, l1->b1, l2->b0
        node_mfma<<<nNodeBlocks, 384, 0, stream>>>(hh, hl,
            WcNh + (size_t)l * WCN_ELEMS, WcNl + (size_t)l * WCN_ELEMS,
            cbf[l], cbs[l], D, S);
        hipMemsetAsync(aggb, 0, HB, stream);
        if (use_eb)
            edge_mfma4<true><<<nEdgeBlocks, 384, 0, stream>>>(s_src, s_dst, perm, ea,
                ebh, ebl, WcEh + (size_t)l * WCE_ELEMS, WcEl + (size_t)l * WCE_ELEMS,
                D, S, aggb, nEdgeBlocks);
        else
            edge_mfma4<false><<<nEdgeBlocks, 384, 0, stream>>>(s_src, s_dst, perm, ea,
                ebh, ebl, WcEh + (size_t)l * WCE_ELEMS, WcEl + (size_t)l * WCE_ELEMS,
                D, S, aggb, nEdgeBlocks);
        node_update_fused<<<2048, 256, 0, stream>>>(xres, aggb, hh, hl);
    }

    // fc1 twice: b0 -> b1 -> b0
    fc_node_kernel<<<fcBlocks, 256, 0, stream>>>(b0, fc1W, fc1b, b1);
    fc_node_kernel<<<fcBlocks, 256, 0, stream>>>(b1, fc1W, fc1b, b0);

    pool_kernel<<<NF, 256, 0, stream>>>(b0, pooled);
    mlp_kernel<<<1, 1024, 0, stream>>>(pooled, glob, W2, b2, W3, b3, W4, b4,
                                       W5, b5, W6, b6, W7, b7, out);
}